// Round 6
// baseline (843.694 us; speedup 1.0000x reference)
//
#include <hip/hip_runtime.h>
#include <hip/hip_bf16.h>
#include <stdint.h>

// MultiHeadDiffAttention — R6. Resolved I/O conventions (6-round evidence):
// inputs f32, OUTPUT f32 (threshold lacks bf16 floor; R2/R3 identical absmax
// = correct compute + wrong out dtype). R2's MFMA pipeline + f32 final epilogue.
// B=2, T=2048, C=1024, H=16, HS=64.

#define T_SEQ 2048

typedef unsigned short u16;
typedef __attribute__((ext_vector_type(8))) short short8;
typedef __attribute__((ext_vector_type(4))) float f32x4;

#define LAMBDA_INIT 0.35550906759096926f
#define ONE_MINUS_LI 0.6444909324090307f
#define SM_SCALE 0.125f

__device__ __forceinline__ u16 f2bf(float f) {
  uint32_t u = __float_as_uint(f);
  return (u16)((u + 0x7FFFu + ((u >> 16) & 1u)) >> 16);
}
__device__ __forceinline__ short8 ld8(const u16* p) {
  return *reinterpret_cast<const short8*>(p);
}
__device__ __forceinline__ f32x4 mfma16(short8 a, short8 b, f32x4 c) {
  return __builtin_amdgcn_mfma_f32_16x16x32_bf16(a, b, c, 0, 0, 0);
}

// ---------------- elementwise f32 -> bf16 ----------------
__global__ __launch_bounds__(256) void cvt_bf16(const float* __restrict__ in,
                                                u16* __restrict__ out, int n) {
  int i = (blockIdx.x * 256 + threadIdx.x) * 4;
  if (i >= n) return;
  float4 f = *reinterpret_cast<const float4*>(in + i);
  union { u16 u[4]; uint2 v; } pk;
  pk.u[0] = f2bf(f.x); pk.u[1] = f2bf(f.y); pk.u[2] = f2bf(f.z); pk.u[3] = f2bf(f.w);
  *reinterpret_cast<uint2*>(out + i) = pk.v;
}

// ------------- transpose + convert: W[K][N] f32 -> WT[N][K] bf16 -------------
__global__ __launch_bounds__(256) void tcvt(const float* __restrict__ W,
                                            u16* __restrict__ WT,
                                            int K, int N, int outRowOff) {
  __shared__ float tile[32][33];
  int n0 = blockIdx.x * 32, k0 = blockIdx.y * 32;
  int tx = threadIdx.x & 31, ty = threadIdx.x >> 5;  // ty 0..7
#pragma unroll
  for (int p = 0; p < 4; ++p)
    tile[ty + 8 * p][tx] = W[(size_t)(k0 + ty + 8 * p) * N + n0 + tx];
  __syncthreads();
#pragma unroll
  for (int p = 0; p < 4; ++p)
    WT[(size_t)(outRowOff + n0 + ty + 8 * p) * K + k0 + tx] = f2bf(tile[tx][ty + 8 * p]);
}

// ---------------- concat two 1024-float biases ----------------
__global__ __launch_bounds__(256) void bias_concat(const float* __restrict__ b1,
                                                   const float* __restrict__ b2,
                                                   float* __restrict__ out) {
  int i = blockIdx.x * 256 + threadIdx.x;  // 0..2047
  out[i] = (i < 1024) ? b1[i] : b2[i - 1024];
}

// ---------------- GEMM: C[M][N] = A[M][K] @ BT[N][K]^T + bias ----------------
// EPI 0: bf16 [M][N].  EPI 1: bf16 vvT ((b*2048+col)*2048 + t).  EPI 2: f32 [M][N].
#define BM 128
#define BN 128
#define BK 32

template <int EPI>
__global__ __launch_bounds__(256) void gemm_bt(const u16* __restrict__ A,
                                               const u16* __restrict__ BT,
                                               const float* __restrict__ bias,
                                               void* __restrict__ Cv,
                                               int M, int N, int K) {
  __shared__ __align__(16) u16 As[BM * BK];
  __shared__ __align__(16) u16 Bs[BN * BK];
  int t = threadIdx.x;
  int w = t >> 6, l = t & 63;
  int g = l >> 4, c16 = l & 15;
  int wr = w >> 1, wc = w & 1;
  size_t gm = (size_t)blockIdx.y * BM, gn = (size_t)blockIdx.x * BN;

  f32x4 acc[4][4] = {};

  int srow = w * 16 + (l >> 2);  // staged row within 64-row chunk (incl. wave)
  int scol = (l & 3) * 8;        // staged col (8 bf16 = 16B)
  const u16* Ag = A + (gm + srow) * (size_t)K + scol;
  const u16* Bg = BT + (gn + srow) * (size_t)K + scol;

  for (int kt = 0; kt < K; kt += BK) {
    __syncthreads();
#pragma unroll
    for (int ca = 0; ca < 2; ++ca) {
      __builtin_amdgcn_global_load_lds(
          (const __attribute__((address_space(1))) void*)(Ag + (size_t)(ca * 64) * K + kt),
          (__attribute__((address_space(3))) void*)&As[(ca * 64 + w * 16) * BK], 16, 0, 0);
      __builtin_amdgcn_global_load_lds(
          (const __attribute__((address_space(1))) void*)(Bg + (size_t)(ca * 64) * K + kt),
          (__attribute__((address_space(3))) void*)&Bs[(ca * 64 + w * 16) * BK], 16, 0, 0);
    }
    __syncthreads();
    short8 af[4], bf[4];
#pragma unroll
    for (int m = 0; m < 4; ++m)
      af[m] = *reinterpret_cast<const short8*>(&As[(wr * 64 + m * 16 + c16) * BK + g * 8]);
#pragma unroll
    for (int n = 0; n < 4; ++n)
      bf[n] = *reinterpret_cast<const short8*>(&Bs[(wc * 64 + n * 16 + c16) * BK + g * 8]);
#pragma unroll
    for (int m = 0; m < 4; ++m)
#pragma unroll
      for (int n = 0; n < 4; ++n)
        acc[m][n] = mfma16(af[m], bf[n], acc[m][n]);
  }

#pragma unroll
  for (int m = 0; m < 4; ++m)
#pragma unroll
    for (int n = 0; n < 4; ++n) {
      int row0 = (int)gm + wr * 64 + m * 16 + g * 4;
      int col = (int)gn + wc * 64 + n * 16 + c16;
      float bz = bias[col];
      if (EPI == 0) {
        u16* C = (u16*)Cv;
#pragma unroll
        for (int r = 0; r < 4; ++r)
          C[(size_t)(row0 + r) * N + col] = f2bf(acc[m][n][r] + bz);
      } else if (EPI == 1) {
        // vvT: row0 = b*2048 + t ; col = h*128 + d -> idx (b*2048+col)*2048 + t
        u16* C = (u16*)Cv;
        int bb = row0 >> 11, tt = row0 & 2047;
        union { u16 u[4]; uint2 v; } pk;
#pragma unroll
        for (int r = 0; r < 4; ++r) pk.u[r] = f2bf(acc[m][n][r] + bz);
        *reinterpret_cast<uint2*>(&C[((size_t)(bb * 2048 + col)) * 2048 + tt]) = pk.v;
      } else {
        float* C = (float*)Cv;
#pragma unroll
        for (int r = 0; r < 4; ++r)
          C[(size_t)(row0 + r) * N + col] = acc[m][n][r] + bz;
      }
    }
}

// ---------------- differential flash attention + fused LN ----------------
// grid (T/64, B*H), block 256. Wave w owns q-rows [bx*64 + w*16, +16).
__global__ __launch_bounds__(256) void diffattn(
    const u16* __restrict__ q1q2, const u16* __restrict__ k1k2,
    const u16* __restrict__ vvT, const int* __restrict__ mask,
    const float* __restrict__ lq1, const float* __restrict__ lk1,
    const float* __restrict__ lq2, const float* __restrict__ lk2,
    const float* __restrict__ lnw, const float* __restrict__ lnb,
    u16* __restrict__ yout) {
  __shared__ __align__(16) u16 Plds[4][2][16][40];  // wave-private, 80B row stride

  int tid = threadIdx.x;
  int w = tid >> 6, l = tid & 63, g = l >> 4, c16 = l & 15;
  int bh = blockIdx.y, b = bh >> 4, h = bh & 15;
  int qr0 = blockIdx.x * 64 + w * 16;

  // lambda = exp(lq1.lk1) - exp(lq2.lk2) + lambda_init  (per head)
  float lm1 = lq1[h * 64 + l] * lk1[h * 64 + l];
  float lm2 = lq2[h * 64 + l] * lk2[h * 64 + l];
#pragma unroll
  for (int off = 32; off; off >>= 1) {
    lm1 += __shfl_xor(lm1, off);
    lm2 += __shfl_xor(lm2, off);
  }
  float lam = __expf(lm1) - __expf(lm2) + LAMBDA_INIT;

  // Q fragments (row = c16, k = g*8+j within each 32-chunk)
  size_t rowQ = (size_t)(b * T_SEQ + qr0 + c16) * 2048 + h * 64 + g * 8;
  short8 q1a[2], q2a[2];
  q1a[0] = ld8(q1q2 + rowQ);        q1a[1] = ld8(q1q2 + rowQ + 32);
  q2a[0] = ld8(q1q2 + rowQ + 1024); q2a[1] = ld8(q1q2 + rowQ + 1056);

  int mq[4];
#pragma unroll
  for (int r = 0; r < 4; ++r) mq[r] = mask[b * T_SEQ + qr0 + g * 4 + r];

  float wln[8], bln[8];
#pragma unroll
  for (int dn = 0; dn < 8; ++dn) {
    wln[dn] = lnw[dn * 16 + c16];
    bln[dn] = lnb[dn * 16 + c16];
  }

  f32x4 acc1[8] = {}, acc2[8] = {};
  float M1[4], L1[4], M2[4], L2[4];
#pragma unroll
  for (int r = 0; r < 4; ++r) { M1[r] = -INFINITY; M2[r] = -INFINITY; L1[r] = 0.f; L2[r] = 0.f; }

  const u16* kbase0 = k1k2 + (size_t)(b * T_SEQ + c16) * 2048 + h * 64 + g * 8;
  const u16* vbase = vvT + ((size_t)(b * 16 + h) * 128 + c16) * 2048 + g * 8;

  for (int kt = 0; kt < T_SEQ; kt += 32) {
    const u16* kb = kbase0 + (size_t)kt * 2048;
    short8 k1f[2][2], k2f[2][2];
#pragma unroll
    for (int n = 0; n < 2; ++n)
#pragma unroll
      for (int c = 0; c < 2; ++c) {
        k1f[n][c] = ld8(kb + (size_t)n * 16 * 2048 + c * 32);
        k2f[n][c] = ld8(kb + (size_t)n * 16 * 2048 + 1024 + c * 32);
      }
    f32x4 s1[2], s2[2];
#pragma unroll
    for (int n = 0; n < 2; ++n) {
      f32x4 t1 = {}; t1 = mfma16(q1a[0], k1f[n][0], t1); t1 = mfma16(q1a[1], k1f[n][1], t1);
      s1[n] = t1;
      f32x4 t2 = {}; t2 = mfma16(q2a[0], k2f[n][0], t2); t2 = mfma16(q2a[1], k2f[n][1], t2);
      s2[n] = t2;
    }
    // scale + query-row mask
#pragma unroll
    for (int n = 0; n < 2; ++n)
#pragma unroll
      for (int r = 0; r < 4; ++r) {
        float x1 = s1[n][r] * SM_SCALE, x2 = s2[n][r] * SM_SCALE;
        if (mq[r] == 0) { x1 = -1e9f; x2 = -1e9f; }
        s1[n][r] = x1; s2[n][r] = x2;
      }
    // tile row-max (reduce over 16 key-lanes)
    float t1v[4], t2v[4];
#pragma unroll
    for (int r = 0; r < 4; ++r) {
      t1v[r] = fmaxf(s1[0][r], s1[1][r]);
      t2v[r] = fmaxf(s2[0][r], s2[1][r]);
    }
#pragma unroll
    for (int off = 1; off < 16; off <<= 1)
#pragma unroll
      for (int r = 0; r < 4; ++r) {
        t1v[r] = fmaxf(t1v[r], __shfl_xor(t1v[r], off));
        t2v[r] = fmaxf(t2v[r], __shfl_xor(t2v[r], off));
      }
    float p1v[2][4], p2v[2][4], rs1[4], rs2[4], a1v[4], a2v[4];
#pragma unroll
    for (int r = 0; r < 4; ++r) {
      float Mn1 = fmaxf(M1[r], t1v[r]);
      a1v[r] = __expf(M1[r] - Mn1); M1[r] = Mn1;
      p1v[0][r] = __expf(s1[0][r] - Mn1); p1v[1][r] = __expf(s1[1][r] - Mn1);
      rs1[r] = p1v[0][r] + p1v[1][r];
      float Mn2 = fmaxf(M2[r], t2v[r]);
      a2v[r] = __expf(M2[r] - Mn2); M2[r] = Mn2;
      p2v[0][r] = __expf(s2[0][r] - Mn2); p2v[1][r] = __expf(s2[1][r] - Mn2);
      rs2[r] = p2v[0][r] + p2v[1][r];
    }
#pragma unroll
    for (int off = 1; off < 16; off <<= 1)
#pragma unroll
      for (int r = 0; r < 4; ++r) {
        rs1[r] += __shfl_xor(rs1[r], off);
        rs2[r] += __shfl_xor(rs2[r], off);
      }
#pragma unroll
    for (int r = 0; r < 4; ++r) {
      L1[r] = L1[r] * a1v[r] + rs1[r];
      L2[r] = L2[r] * a2v[r] + rs2[r];
    }
#pragma unroll
    for (int dn = 0; dn < 8; ++dn)
#pragma unroll
      for (int r = 0; r < 4; ++r) {
        acc1[dn][r] *= a1v[r];
        acc2[dn][r] *= a2v[r];
      }
    // P (D-layout) -> LDS -> A-fragment layout (wave-private, no barrier)
#pragma unroll
    for (int n = 0; n < 2; ++n)
#pragma unroll
      for (int r = 0; r < 4; ++r) {
        Plds[w][0][g * 4 + r][n * 16 + c16] = f2bf(p1v[n][r]);
        Plds[w][1][g * 4 + r][n * 16 + c16] = f2bf(p2v[n][r]);
      }
    short8 pa1 = *reinterpret_cast<const short8*>(&Plds[w][0][c16][g * 8]);
    short8 pa2 = *reinterpret_cast<const short8*>(&Plds[w][1][c16][g * 8]);
#pragma unroll
    for (int dn = 0; dn < 8; ++dn) {
      short8 vf = ld8(vbase + (size_t)(dn * 16) * 2048 + kt);
      acc1[dn] = mfma16(pa1, vf, acc1[dn]);
      acc2[dn] = mfma16(pa2, vf, acc2[dn]);
    }
  }

  // epilogue: y = acc1/L1 - lam*acc2/L2, per-row LN over 128, store bf16
  float y[8][4];
#pragma unroll
  for (int dn = 0; dn < 8; ++dn)
#pragma unroll
    for (int r = 0; r < 4; ++r)
      y[dn][r] = acc1[dn][r] / L1[r] - lam * (acc2[dn][r] / L2[r]);
#pragma unroll
  for (int r = 0; r < 4; ++r) {
    float s = 0.f;
#pragma unroll
    for (int dn = 0; dn < 8; ++dn) s += y[dn][r];
#pragma unroll
    for (int off = 1; off < 16; off <<= 1) s += __shfl_xor(s, off);
    float u = s * (1.f / 128.f);
    float v = 0.f;
#pragma unroll
    for (int dn = 0; dn < 8; ++dn) { float d = y[dn][r] - u; v += d * d; }
#pragma unroll
    for (int off = 1; off < 16; off <<= 1) v += __shfl_xor(v, off);
    float rstd = rsqrtf(v * (1.f / 128.f) + 1e-12f);
#pragma unroll
    for (int dn = 0; dn < 8; ++dn)
      y[dn][r] = (wln[dn] * ((y[dn][r] - u) * rstd) + bln[dn]) * ONE_MINUS_LI;
  }
#pragma unroll
  for (int dn = 0; dn < 8; ++dn)
#pragma unroll
    for (int r = 0; r < 4; ++r)
      yout[(size_t)(b * T_SEQ + qr0 + g * 4 + r) * 2048 + h * 128 + dn * 16 + c16] =
          f2bf(y[dn][r]);
}

// ---------------- host ----------------
extern "C" void kernel_launch(void* const* d_in, const int* in_sizes, int n_in,
                              void* d_out, int out_size, void* d_ws, size_t ws_size,
                              hipStream_t stream) {
  (void)in_sizes; (void)n_in; (void)out_size; (void)ws_size;
  const float* q   = (const float*)d_in[0];
  const float* k   = (const float*)d_in[1];
  const float* v   = (const float*)d_in[2];
  const int* maskp = (const int*)d_in[3];
  const float* Wq1 = (const float*)d_in[4];
  const float* bq1 = (const float*)d_in[5];
  const float* Wq2 = (const float*)d_in[6];
  const float* bq2 = (const float*)d_in[7];
  const float* Wk1 = (const float*)d_in[8];
  const float* bk1 = (const float*)d_in[9];
  const float* Wk2 = (const float*)d_in[10];
  const float* bk2 = (const float*)d_in[11];
  const float* Wv  = (const float*)d_in[12];
  const float* bv  = (const float*)d_in[13];
  const float* Wc  = (const float*)d_in[14];
  const float* bc  = (const float*)d_in[15];
  const float* lnw = (const float*)d_in[16];
  const float* lnb = (const float*)d_in[17];
  const float* lq1 = (const float*)d_in[18];
  const float* lk1 = (const float*)d_in[19];
  const float* lq2 = (const float*)d_in[20];
  const float* lk2 = (const float*)d_in[21];

  char* ws = (char*)d_ws;
  u16* qb     = (u16*)(ws + 0);
  u16* kb     = (u16*)(ws + 8388608);
  u16* vb     = (u16*)(ws + 16777216);
  u16* Wq12T  = (u16*)(ws + 25165824);
  u16* Wk12T  = (u16*)(ws + 29360128);
  u16* WvT    = (u16*)(ws + 33554432);
  u16* WcT    = (u16*)(ws + 37748736);
  float* biasq = (float*)(ws + 41943040);
  float* biask = (float*)(ws + 41951232);
  u16* q1q2   = (u16*)(ws + 41959424);
  u16* k1k2   = (u16*)(ws + 58736640);
  u16* vvT    = (u16*)(ws + 75513856);
  u16* yb     = (u16*)(ws + 0);  // alias qb+kb (16MB; both dead before attention)

  const int NELEM = 2 * T_SEQ * 1024;  // 4,194,304

  cvt_bf16<<<4096, 256, 0, stream>>>(q, qb, NELEM);
  cvt_bf16<<<4096, 256, 0, stream>>>(k, kb, NELEM);
  cvt_bf16<<<4096, 256, 0, stream>>>(v, vb, NELEM);

  tcvt<<<dim3(32, 32), 256, 0, stream>>>(Wq1, Wq12T, 1024, 1024, 0);
  tcvt<<<dim3(32, 32), 256, 0, stream>>>(Wq2, Wq12T, 1024, 1024, 1024);
  tcvt<<<dim3(32, 32), 256, 0, stream>>>(Wk1, Wk12T, 1024, 1024, 0);
  tcvt<<<dim3(32, 32), 256, 0, stream>>>(Wk2, Wk12T, 1024, 1024, 1024);
  tcvt<<<dim3(64, 32), 256, 0, stream>>>(Wv, WvT, 1024, 2048, 0);
  tcvt<<<dim3(32, 64), 256, 0, stream>>>(Wc, WcT, 2048, 1024, 0);

  bias_concat<<<8, 256, 0, stream>>>(bq1, bq2, biasq);
  bias_concat<<<8, 256, 0, stream>>>(bk1, bk2, biask);

  gemm_bt<0><<<dim3(16, 32), 256, 0, stream>>>(qb, Wq12T, biasq, q1q2, 4096, 2048, 1024);
  gemm_bt<0><<<dim3(16, 32), 256, 0, stream>>>(kb, Wk12T, biask, k1k2, 4096, 2048, 1024);
  gemm_bt<1><<<dim3(16, 32), 256, 0, stream>>>(vb, WvT, bv, vvT, 4096, 2048, 1024);

  diffattn<<<dim3(32, 32), 256, 0, stream>>>(q1q2, k1k2, vvT, maskp,
                                             lq1, lk1, lq2, lk2, lnw, lnb, yb);

  gemm_bt<2><<<dim3(8, 32), 256, 0, stream>>>(yb, WcT, bc, d_out, 4096, 1024, 2048);
}

// Round 7
// 527.494 us; speedup vs baseline: 1.5994x; 1.5994x over previous
//
#include <hip/hip_runtime.h>
#include <hip/hip_bf16.h>
#include <stdint.h>

// MultiHeadDiffAttention — R7. R6 passed (844us, diffattn=707us latency-bound:
// MfmaUtil 6%, occ 12%, 2.1M LDS conflicts). Rewrite diffattn with 32x32
// swapped-operand MFMA: lane-owns-q-row softmax (in-lane reduce + 1 shfl),
// in-register P-frag build (cvt_pk + cross-half shfl), swapped PV, and
// att1/att2 split across wave pairs (lower VGPR, shorter chain).
// B=2, T=2048, C=1024, H=16, HS=64.

#define T_SEQ 2048

typedef unsigned short u16;
typedef __attribute__((ext_vector_type(8))) short short8;
typedef __attribute__((ext_vector_type(4))) float f32x4;
typedef __attribute__((ext_vector_type(16))) float f32x16;

#define LAMBDA_INIT 0.35550906759096926f
#define ONE_MINUS_LI 0.6444909324090307f
#define SM_SCALE 0.125f

__device__ __forceinline__ u16 f2bf(float f) {
  uint32_t u = __float_as_uint(f);
  return (u16)((u + 0x7FFFu + ((u >> 16) & 1u)) >> 16);
}
__device__ __forceinline__ short8 ld8(const u16* p) {
  return *reinterpret_cast<const short8*>(p);
}
__device__ __forceinline__ f32x4 mfma16(short8 a, short8 b, f32x4 c) {
  return __builtin_amdgcn_mfma_f32_16x16x32_bf16(a, b, c, 0, 0, 0);
}
__device__ __forceinline__ f32x16 mfma32(short8 a, short8 b, f32x16 c) {
  return __builtin_amdgcn_mfma_f32_32x32x16_bf16(a, b, c, 0, 0, 0);
}
__device__ __forceinline__ uint32_t cvtpk(float lo, float hi_) {
  uint32_t r;
  asm("v_cvt_pk_bf16_f32 %0, %1, %2" : "=v"(r) : "v"(lo), "v"(hi_));
  return r;
}

// ---------------- elementwise f32 -> bf16 ----------------
__global__ __launch_bounds__(256) void cvt_bf16(const float* __restrict__ in,
                                                u16* __restrict__ out, int n) {
  int i = (blockIdx.x * 256 + threadIdx.x) * 4;
  if (i >= n) return;
  float4 f = *reinterpret_cast<const float4*>(in + i);
  union { u16 u[4]; uint2 v; } pk;
  pk.u[0] = f2bf(f.x); pk.u[1] = f2bf(f.y); pk.u[2] = f2bf(f.z); pk.u[3] = f2bf(f.w);
  *reinterpret_cast<uint2*>(out + i) = pk.v;
}

// ------------- transpose + convert: W[K][N] f32 -> WT[N][K] bf16 -------------
__global__ __launch_bounds__(256) void tcvt(const float* __restrict__ W,
                                            u16* __restrict__ WT,
                                            int K, int N, int outRowOff) {
  __shared__ float tile[32][33];
  int n0 = blockIdx.x * 32, k0 = blockIdx.y * 32;
  int tx = threadIdx.x & 31, ty = threadIdx.x >> 5;  // ty 0..7
#pragma unroll
  for (int p = 0; p < 4; ++p)
    tile[ty + 8 * p][tx] = W[(size_t)(k0 + ty + 8 * p) * N + n0 + tx];
  __syncthreads();
#pragma unroll
  for (int p = 0; p < 4; ++p)
    WT[(size_t)(outRowOff + n0 + ty + 8 * p) * K + k0 + tx] = f2bf(tile[tx][ty + 8 * p]);
}

// ---------------- concat two 1024-float biases ----------------
__global__ __launch_bounds__(256) void bias_concat(const float* __restrict__ b1,
                                                   const float* __restrict__ b2,
                                                   float* __restrict__ out) {
  int i = blockIdx.x * 256 + threadIdx.x;  // 0..2047
  out[i] = (i < 1024) ? b1[i] : b2[i - 1024];
}

// ---------------- GEMM: C[M][N] = A[M][K] @ BT[N][K]^T + bias ----------------
// EPI 0: bf16 [M][N].  EPI 1: bf16 vvT ((b*2048+col)*2048 + t).  EPI 2: f32 [M][N].
#define BM 128
#define BN 128
#define BK 32

template <int EPI>
__global__ __launch_bounds__(256) void gemm_bt(const u16* __restrict__ A,
                                               const u16* __restrict__ BT,
                                               const float* __restrict__ bias,
                                               void* __restrict__ Cv,
                                               int M, int N, int K) {
  __shared__ __align__(16) u16 As[BM * BK];
  __shared__ __align__(16) u16 Bs[BN * BK];
  int t = threadIdx.x;
  int w = t >> 6, l = t & 63;
  int g = l >> 4, c16 = l & 15;
  int wr = w >> 1, wc = w & 1;
  size_t gm = (size_t)blockIdx.y * BM, gn = (size_t)blockIdx.x * BN;

  f32x4 acc[4][4] = {};

  int srow = w * 16 + (l >> 2);  // staged row within 64-row chunk (incl. wave)
  int scol = (l & 3) * 8;        // staged col (8 bf16 = 16B)
  const u16* Ag = A + (gm + srow) * (size_t)K + scol;
  const u16* Bg = BT + (gn + srow) * (size_t)K + scol;

  for (int kt = 0; kt < K; kt += BK) {
    __syncthreads();
#pragma unroll
    for (int ca = 0; ca < 2; ++ca) {
      __builtin_amdgcn_global_load_lds(
          (const __attribute__((address_space(1))) void*)(Ag + (size_t)(ca * 64) * K + kt),
          (__attribute__((address_space(3))) void*)&As[(ca * 64 + w * 16) * BK], 16, 0, 0);
      __builtin_amdgcn_global_load_lds(
          (const __attribute__((address_space(1))) void*)(Bg + (size_t)(ca * 64) * K + kt),
          (__attribute__((address_space(3))) void*)&Bs[(ca * 64 + w * 16) * BK], 16, 0, 0);
    }
    __syncthreads();
    short8 af[4], bf[4];
#pragma unroll
    for (int m = 0; m < 4; ++m)
      af[m] = *reinterpret_cast<const short8*>(&As[(wr * 64 + m * 16 + c16) * BK + g * 8]);
#pragma unroll
    for (int n = 0; n < 4; ++n)
      bf[n] = *reinterpret_cast<const short8*>(&Bs[(wc * 64 + n * 16 + c16) * BK + g * 8]);
#pragma unroll
    for (int m = 0; m < 4; ++m)
#pragma unroll
      for (int n = 0; n < 4; ++n)
        acc[m][n] = mfma16(af[m], bf[n], acc[m][n]);
  }

#pragma unroll
  for (int m = 0; m < 4; ++m)
#pragma unroll
    for (int n = 0; n < 4; ++n) {
      int row0 = (int)gm + wr * 64 + m * 16 + g * 4;
      int col = (int)gn + wc * 64 + n * 16 + c16;
      float bz = bias[col];
      if (EPI == 0) {
        u16* C = (u16*)Cv;
#pragma unroll
        for (int r = 0; r < 4; ++r)
          C[(size_t)(row0 + r) * N + col] = f2bf(acc[m][n][r] + bz);
      } else if (EPI == 1) {
        u16* C = (u16*)Cv;
        int bb = row0 >> 11, tt = row0 & 2047;
        union { u16 u[4]; uint2 v; } pk;
#pragma unroll
        for (int r = 0; r < 4; ++r) pk.u[r] = f2bf(acc[m][n][r] + bz);
        *reinterpret_cast<uint2*>(&C[((size_t)(bb * 2048 + col)) * 2048 + tt]) = pk.v;
      } else {
        float* C = (float*)Cv;
#pragma unroll
        for (int r = 0; r < 4; ++r)
          C[(size_t)(row0 + r) * N + col] = acc[m][n][r] + bz;
      }
    }
}

// ---------------- differential flash attention + fused LN (32x32 swapped) ----
// grid (T/64, B*H), block 256 = 4 waves = 2 pairs. Pair p covers q-rows
// [bx*64 + p*32, +32); wave stream s in {0,1} handles attention stream s+1.
// Per lane: q = l&31 (owns one q-row), hi = l>>5 (key/d half).
__global__ __launch_bounds__(256, 2) void diffattn(
    const u16* __restrict__ q1q2, const u16* __restrict__ k1k2,
    const u16* __restrict__ vvT, const int* __restrict__ mask,
    const float* __restrict__ lq1, const float* __restrict__ lk1,
    const float* __restrict__ lq2, const float* __restrict__ lk2,
    const float* __restrict__ lnw, const float* __restrict__ lnb,
    u16* __restrict__ yout) {
  __shared__ float ylds[2][64][65];  // [pair][lane][64 d-values], pad->2-way free

  int tid = threadIdx.x;
  int w = tid >> 6, l = tid & 63;
  int q = l & 31, hi = l >> 5;
  int pair = w >> 1, stream = w & 1;
  int bh = blockIdx.y, b = bh >> 4, h = bh & 15;
  int qr0 = blockIdx.x * 64 + pair * 32;

  // lambda = exp(lq1.lk1) - exp(lq2.lk2) + lambda_init  (per head)
  float lm1 = lq1[h * 64 + l] * lk1[h * 64 + l];
  float lm2 = lq2[h * 64 + l] * lk2[h * 64 + l];
#pragma unroll
  for (int o = 32; o; o >>= 1) {
    lm1 += __shfl_xor(lm1, o);
    lm2 += __shfl_xor(lm2, o);
  }
  float lam = __expf(lm1) - __expf(lm2) + LAMBDA_INIT;

  int soff = stream * 1024;
  // Q^T B-frags: lane holds Q[q][c*16 + hi*8 + j]
  const u16* qrow = q1q2 + (size_t)(b * T_SEQ + qr0 + q) * 2048 + h * 64 + soff + hi * 8;
  short8 qf[4];
#pragma unroll
  for (int c = 0; c < 4; ++c) qf[c] = ld8(qrow + c * 16);

  bool msk = (mask[b * T_SEQ + qr0 + q] == 0);

  float M = -INFINITY, L = 0.f;
  f32x16 acc[4] = {};

  const u16* kbase = k1k2 + (size_t)(b * T_SEQ) * 2048 + h * 64 + soff + hi * 8;
  const u16* vbase = vvT + ((size_t)(b * 16 + h) * 128 + q) * 2048 + hi * 8;

  for (int kt = 0; kt < T_SEQ; kt += 32) {
    // K A-frags: lane holds K[kt + q_sym][c*16 + hi*8 + j] (row index = l&31 = key)
    const u16* krow = kbase + (size_t)(kt + q) * 2048;
    short8 kf[4];
#pragma unroll
    for (int c = 0; c < 4; ++c) kf[c] = ld8(krow + c * 16);

    // S^T[key][q]: D row = key = (r&3)+8*(r>>2)+4*hi, col = q = l&31
    f32x16 s = {};
#pragma unroll
    for (int c = 0; c < 4; ++c) s = mfma32(kf[c], qf[c], s);

    float x[16];
#pragma unroll
    for (int r = 0; r < 16; ++r) x[r] = msk ? -1e9f : s[r] * SM_SCALE;

    // row max: in-lane tree over 16 + cross-half
    float t8[8], t4[4];
#pragma unroll
    for (int i = 0; i < 8; ++i) t8[i] = fmaxf(x[i], x[i + 8]);
#pragma unroll
    for (int i = 0; i < 4; ++i) t4[i] = fmaxf(t8[i], t8[i + 4]);
    float tm = fmaxf(fmaxf(t4[0], t4[1]), fmaxf(t4[2], t4[3]));
    tm = fmaxf(tm, __shfl_xor(tm, 32));

    float Mn = fmaxf(M, tm);
    float a = __expf(M - Mn);
    float p[16];
#pragma unroll
    for (int r = 0; r < 16; ++r) p[r] = __expf(x[r] - Mn);
    float s8[8], s4[4];
#pragma unroll
    for (int i = 0; i < 8; ++i) s8[i] = p[i] + p[i + 8];
#pragma unroll
    for (int i = 0; i < 4; ++i) s4[i] = s8[i] + s8[i + 4];
    float ps = (s4[0] + s4[1]) + (s4[2] + s4[3]);
    ps += __shfl_xor(ps, 32);
    L = L * a + ps;
    M = Mn;
#pragma unroll
    for (int d = 0; d < 4; ++d) acc[d] *= a;

    // P^T B-frags in-register: word (j0,j1) = keys hi*8+{0,1} of each 16-slot
    uint32_t a1 = cvtpk(p[0], p[1]), a2 = cvtpk(p[2], p[3]);
    uint32_t b1 = cvtpk(p[4], p[5]), b2 = cvtpk(p[6], p[7]);
    uint32_t c1 = cvtpk(p[8], p[9]), c2 = cvtpk(p[10], p[11]);
    uint32_t d1 = cvtpk(p[12], p[13]), d2 = cvtpk(p[14], p[15]);
    uint32_t sa1 = (uint32_t)__shfl_xor((int)a1, 32), sa2 = (uint32_t)__shfl_xor((int)a2, 32);
    uint32_t sb1 = (uint32_t)__shfl_xor((int)b1, 32), sb2 = (uint32_t)__shfl_xor((int)b2, 32);
    uint32_t sc1 = (uint32_t)__shfl_xor((int)c1, 32), sc2 = (uint32_t)__shfl_xor((int)c2, 32);
    uint32_t sd1 = (uint32_t)__shfl_xor((int)d1, 32), sd2 = (uint32_t)__shfl_xor((int)d2, 32);
    union { uint32_t u[4]; short8 s8v; } pu0, pu1;
    pu0.u[0] = hi ? sb1 : a1;  pu0.u[1] = hi ? sb2 : a2;
    pu0.u[2] = hi ? b1 : sa1;  pu0.u[3] = hi ? b2 : sa2;
    pu1.u[0] = hi ? sd1 : c1;  pu1.u[1] = hi ? sd2 : c2;
    pu1.u[2] = hi ? d1 : sc1;  pu1.u[3] = hi ? d2 : sc2;
    short8 pf0 = pu0.s8v, pf1 = pu1.s8v;

    // swapped PV: acc[dchunk] row = dloc(r,hi), col = q
#pragma unroll
    for (int d = 0; d < 4; ++d) {
      short8 vf0 = ld8(vbase + (size_t)(d * 32) * 2048 + kt);
      short8 vf1 = ld8(vbase + (size_t)(d * 32) * 2048 + kt + 16);
      acc[d] = mfma32(vf0, pf0, acc[d]);
      acc[d] = mfma32(vf1, pf1, acc[d]);
    }
  }

  float inv = 1.f / L;
  if (stream == 1) {
#pragma unroll
    for (int d = 0; d < 4; ++d)
#pragma unroll
      for (int r = 0; r < 16; ++r)
        ylds[pair][l][d * 16 + r] = acc[d][r] * inv;
  }
  __syncthreads();
  if (stream == 0) {
    float y[4][16];
#pragma unroll
    for (int d = 0; d < 4; ++d)
#pragma unroll
      for (int r = 0; r < 16; ++r)
        y[d][r] = acc[d][r] * inv - lam * ylds[pair][l][d * 16 + r];
    // per-row LN over 128 (lane + partner hold 64 each)
    float sm = 0.f;
#pragma unroll
    for (int d = 0; d < 4; ++d)
#pragma unroll
      for (int r = 0; r < 16; ++r) sm += y[d][r];
    sm += __shfl_xor(sm, 32);
    float u = sm * (1.f / 128.f);
    float var = 0.f;
#pragma unroll
    for (int d = 0; d < 4; ++d)
#pragma unroll
      for (int r = 0; r < 16; ++r) { float dd = y[d][r] - u; var += dd * dd; }
    var += __shfl_xor(var, 32);
    float rstd = rsqrtf(var * (1.f / 128.f) + 1e-12f);

    size_t orow = (size_t)(b * T_SEQ + qr0 + q) * 2048 + h * 128;
#pragma unroll
    for (int d = 0; d < 4; ++d)
#pragma unroll
      for (int rr = 0; rr < 4; ++rr) {
        int base = d * 32 + 8 * rr + 4 * hi;
        union { u16 u[4]; uint2 v; } o;
#pragma unroll
        for (int i = 0; i < 4; ++i) {
          float yv = (lnw[base + i] * ((y[d][rr * 4 + i] - u) * rstd) + lnb[base + i]) *
                     ONE_MINUS_LI;
          o.u[i] = f2bf(yv);
        }
        *reinterpret_cast<uint2*>(&yout[orow + base]) = o.v;
      }
  }
}

// ---------------- host ----------------
extern "C" void kernel_launch(void* const* d_in, const int* in_sizes, int n_in,
                              void* d_out, int out_size, void* d_ws, size_t ws_size,
                              hipStream_t stream) {
  (void)in_sizes; (void)n_in; (void)out_size; (void)ws_size;
  const float* q   = (const float*)d_in[0];
  const float* k   = (const float*)d_in[1];
  const float* v   = (const float*)d_in[2];
  const int* maskp = (const int*)d_in[3];
  const float* Wq1 = (const float*)d_in[4];
  const float* bq1 = (const float*)d_in[5];
  const float* Wq2 = (const float*)d_in[6];
  const float* bq2 = (const float*)d_in[7];
  const float* Wk1 = (const float*)d_in[8];
  const float* bk1 = (const float*)d_in[9];
  const float* Wk2 = (const float*)d_in[10];
  const float* bk2 = (const float*)d_in[11];
  const float* Wv  = (const float*)d_in[12];
  const float* bv  = (const float*)d_in[13];
  const float* Wc  = (const float*)d_in[14];
  const float* bc  = (const float*)d_in[15];
  const float* lnw = (const float*)d_in[16];
  const float* lnb = (const float*)d_in[17];
  const float* lq1 = (const float*)d_in[18];
  const float* lk1 = (const float*)d_in[19];
  const float* lq2 = (const float*)d_in[20];
  const float* lk2 = (const float*)d_in[21];

  char* ws = (char*)d_ws;
  u16* qb     = (u16*)(ws + 0);
  u16* kb     = (u16*)(ws + 8388608);
  u16* vb     = (u16*)(ws + 16777216);
  u16* Wq12T  = (u16*)(ws + 25165824);
  u16* Wk12T  = (u16*)(ws + 29360128);
  u16* WvT    = (u16*)(ws + 33554432);
  u16* WcT    = (u16*)(ws + 37748736);
  float* biasq = (float*)(ws + 41943040);
  float* biask = (float*)(ws + 41951232);
  u16* q1q2   = (u16*)(ws + 41959424);
  u16* k1k2   = (u16*)(ws + 58736640);
  u16* vvT    = (u16*)(ws + 75513856);
  u16* yb     = (u16*)(ws + 0);  // alias qb+kb (16MB; both dead before attention)

  const int NELEM = 2 * T_SEQ * 1024;  // 4,194,304

  cvt_bf16<<<4096, 256, 0, stream>>>(q, qb, NELEM);
  cvt_bf16<<<4096, 256, 0, stream>>>(k, kb, NELEM);
  cvt_bf16<<<4096, 256, 0, stream>>>(v, vb, NELEM);

  tcvt<<<dim3(32, 32), 256, 0, stream>>>(Wq1, Wq12T, 1024, 1024, 0);
  tcvt<<<dim3(32, 32), 256, 0, stream>>>(Wq2, Wq12T, 1024, 1024, 1024);
  tcvt<<<dim3(32, 32), 256, 0, stream>>>(Wk1, Wk12T, 1024, 1024, 0);
  tcvt<<<dim3(32, 32), 256, 0, stream>>>(Wk2, Wk12T, 1024, 1024, 1024);
  tcvt<<<dim3(64, 32), 256, 0, stream>>>(Wv, WvT, 1024, 2048, 0);
  tcvt<<<dim3(32, 64), 256, 0, stream>>>(Wc, WcT, 2048, 1024, 0);

  bias_concat<<<8, 256, 0, stream>>>(bq1, bq2, biasq);
  bias_concat<<<8, 256, 0, stream>>>(bk1, bk2, biask);

  gemm_bt<0><<<dim3(16, 32), 256, 0, stream>>>(qb, Wq12T, biasq, q1q2, 4096, 2048, 1024);
  gemm_bt<0><<<dim3(16, 32), 256, 0, stream>>>(kb, Wk12T, biask, k1k2, 4096, 2048, 1024);
  gemm_bt<1><<<dim3(16, 32), 256, 0, stream>>>(vb, WvT, bv, vvT, 4096, 2048, 1024);

  diffattn<<<dim3(32, 32), 256, 0, stream>>>(q1q2, k1k2, vvT, maskp,
                                             lq1, lk1, lq2, lk2, lnw, lnb, yb);

  gemm_bt<2><<<dim3(8, 32), 256, 0, stream>>>(yb, WcT, bc, d_out, 4096, 1024, 2048);
}

// Round 8
// 328.781 us; speedup vs baseline: 2.5661x; 1.6044x over previous
//
#include <hip/hip_runtime.h>
#include <hip/hip_bf16.h>
#include <stdint.h>

// MultiHeadDiffAttention — R8. R7 diffattn was TA/latency-bound (12 × 4KB-stride
// 64-lane gathers per iter). This round: cooperative LDS staging of K/V tiles
// (reg-staged, padded rows), T14 prefetch, T13 defer-max, mask folded into scale,
// bf16 ylds overlaid on the staging buffers. GEMM pipeline unchanged (passing).
// B=2, T=2048, C=1024, H=16, HS=64.

#define T_SEQ 2048

typedef unsigned short u16;
typedef __attribute__((ext_vector_type(8))) short short8;
typedef __attribute__((ext_vector_type(4))) float f32x4;
typedef __attribute__((ext_vector_type(16))) float f32x16;

#define LAMBDA_INIT 0.35550906759096926f
#define ONE_MINUS_LI 0.6444909324090307f
#define SM_SCALE 0.125f

__device__ __forceinline__ u16 f2bf(float f) {
  uint32_t u = __float_as_uint(f);
  return (u16)((u + 0x7FFFu + ((u >> 16) & 1u)) >> 16);
}
__device__ __forceinline__ float b2f(u16 u) {
  return __uint_as_float(((uint32_t)u) << 16);
}
__device__ __forceinline__ short8 ld8(const u16* p) {
  return *reinterpret_cast<const short8*>(p);
}
__device__ __forceinline__ void st8(u16* p, short8 v) {
  *reinterpret_cast<short8*>(p) = v;
}
__device__ __forceinline__ f32x4 mfma16(short8 a, short8 b, f32x4 c) {
  return __builtin_amdgcn_mfma_f32_16x16x32_bf16(a, b, c, 0, 0, 0);
}
__device__ __forceinline__ f32x16 mfma32(short8 a, short8 b, f32x16 c) {
  return __builtin_amdgcn_mfma_f32_32x32x16_bf16(a, b, c, 0, 0, 0);
}
__device__ __forceinline__ uint32_t cvtpk(float lo, float hi_) {
  uint32_t r;
  asm("v_cvt_pk_bf16_f32 %0, %1, %2" : "=v"(r) : "v"(lo), "v"(hi_));
  return r;
}

// ---------------- elementwise f32 -> bf16 ----------------
__global__ __launch_bounds__(256) void cvt_bf16(const float* __restrict__ in,
                                                u16* __restrict__ out, int n) {
  int i = (blockIdx.x * 256 + threadIdx.x) * 4;
  if (i >= n) return;
  float4 f = *reinterpret_cast<const float4*>(in + i);
  union { u16 u[4]; uint2 v; } pk;
  pk.u[0] = f2bf(f.x); pk.u[1] = f2bf(f.y); pk.u[2] = f2bf(f.z); pk.u[3] = f2bf(f.w);
  *reinterpret_cast<uint2*>(out + i) = pk.v;
}

// ------------- transpose + convert: W[K][N] f32 -> WT[N][K] bf16 -------------
__global__ __launch_bounds__(256) void tcvt(const float* __restrict__ W,
                                            u16* __restrict__ WT,
                                            int K, int N, int outRowOff) {
  __shared__ float tile[32][33];
  int n0 = blockIdx.x * 32, k0 = blockIdx.y * 32;
  int tx = threadIdx.x & 31, ty = threadIdx.x >> 5;  // ty 0..7
#pragma unroll
  for (int p = 0; p < 4; ++p)
    tile[ty + 8 * p][tx] = W[(size_t)(k0 + ty + 8 * p) * N + n0 + tx];
  __syncthreads();
#pragma unroll
  for (int p = 0; p < 4; ++p)
    WT[(size_t)(outRowOff + n0 + ty + 8 * p) * K + k0 + tx] = f2bf(tile[tx][ty + 8 * p]);
}

// ---------------- concat two 1024-float biases ----------------
__global__ __launch_bounds__(256) void bias_concat(const float* __restrict__ b1,
                                                   const float* __restrict__ b2,
                                                   float* __restrict__ out) {
  int i = blockIdx.x * 256 + threadIdx.x;  // 0..2047
  out[i] = (i < 1024) ? b1[i] : b2[i - 1024];
}

// ---------------- GEMM: C[M][N] = A[M][K] @ BT[N][K]^T + bias ----------------
// EPI 0: bf16 [M][N].  EPI 1: bf16 vvT ((b*2048+col)*2048 + t).  EPI 2: f32 [M][N].
#define BM 128
#define BN 128
#define BK 32

template <int EPI>
__global__ __launch_bounds__(256) void gemm_bt(const u16* __restrict__ A,
                                               const u16* __restrict__ BT,
                                               const float* __restrict__ bias,
                                               void* __restrict__ Cv,
                                               int M, int N, int K) {
  __shared__ __align__(16) u16 As[BM * BK];
  __shared__ __align__(16) u16 Bs[BN * BK];
  int t = threadIdx.x;
  int w = t >> 6, l = t & 63;
  int g = l >> 4, c16 = l & 15;
  int wr = w >> 1, wc = w & 1;
  size_t gm = (size_t)blockIdx.y * BM, gn = (size_t)blockIdx.x * BN;

  f32x4 acc[4][4] = {};

  int srow = w * 16 + (l >> 2);
  int scol = (l & 3) * 8;
  const u16* Ag = A + (gm + srow) * (size_t)K + scol;
  const u16* Bg = BT + (gn + srow) * (size_t)K + scol;

  for (int kt = 0; kt < K; kt += BK) {
    __syncthreads();
#pragma unroll
    for (int ca = 0; ca < 2; ++ca) {
      __builtin_amdgcn_global_load_lds(
          (const __attribute__((address_space(1))) void*)(Ag + (size_t)(ca * 64) * K + kt),
          (__attribute__((address_space(3))) void*)&As[(ca * 64 + w * 16) * BK], 16, 0, 0);
      __builtin_amdgcn_global_load_lds(
          (const __attribute__((address_space(1))) void*)(Bg + (size_t)(ca * 64) * K + kt),
          (__attribute__((address_space(3))) void*)&Bs[(ca * 64 + w * 16) * BK], 16, 0, 0);
    }
    __syncthreads();
    short8 af[4], bf[4];
#pragma unroll
    for (int m = 0; m < 4; ++m)
      af[m] = *reinterpret_cast<const short8*>(&As[(wr * 64 + m * 16 + c16) * BK + g * 8]);
#pragma unroll
    for (int n = 0; n < 4; ++n)
      bf[n] = *reinterpret_cast<const short8*>(&Bs[(wc * 64 + n * 16 + c16) * BK + g * 8]);
#pragma unroll
    for (int m = 0; m < 4; ++m)
#pragma unroll
      for (int n = 0; n < 4; ++n)
        acc[m][n] = mfma16(af[m], bf[n], acc[m][n]);
  }

#pragma unroll
  for (int m = 0; m < 4; ++m)
#pragma unroll
    for (int n = 0; n < 4; ++n) {
      int row0 = (int)gm + wr * 64 + m * 16 + g * 4;
      int col = (int)gn + wc * 64 + n * 16 + c16;
      float bz = bias[col];
      if (EPI == 0) {
        u16* C = (u16*)Cv;
#pragma unroll
        for (int r = 0; r < 4; ++r)
          C[(size_t)(row0 + r) * N + col] = f2bf(acc[m][n][r] + bz);
      } else if (EPI == 1) {
        u16* C = (u16*)Cv;
        int bb = row0 >> 11, tt = row0 & 2047;
        union { u16 u[4]; uint2 v; } pk;
#pragma unroll
        for (int r = 0; r < 4; ++r) pk.u[r] = f2bf(acc[m][n][r] + bz);
        *reinterpret_cast<uint2*>(&C[((size_t)(bb * 2048 + col)) * 2048 + tt]) = pk.v;
      } else {
        float* C = (float*)Cv;
#pragma unroll
        for (int r = 0; r < 4; ++r)
          C[(size_t)(row0 + r) * N + col] = acc[m][n][r] + bz;
      }
    }
}

// ---------------- differential flash attention + fused LN (32x32 swapped) ----
// grid (T/64, B*H), block 256 = 4 waves = 2 pairs. Pair p covers q-rows
// [bx*64 + p*32, +32); wave stream s handles attention stream s+1.
// K/V tiles cooperatively staged in LDS (reg-staged, padded rows).
#define KROW 72   // K row: 64 elems + pad (144B, 16B-aligned, 2/4-way banks)
#define VROW 40   // V row: 32 elems + pad (80B, 16B-aligned, 4-way banks)
#define YROW 72   // ylds row: 64 elems + pad
__global__ __launch_bounds__(256, 3) void diffattn(
    const u16* __restrict__ q1q2, const u16* __restrict__ k1k2,
    const u16* __restrict__ vvT, const int* __restrict__ mask,
    const float* __restrict__ lq1, const float* __restrict__ lk1,
    const float* __restrict__ lq2, const float* __restrict__ lk2,
    const float* __restrict__ lnw, const float* __restrict__ lnb,
    u16* __restrict__ yout) {
  // Ks: [2][32][KROW] = 4608 elems ; Vs: [128][VROW] = 5120 elems ; total 9728
  // ylds overlay: [2][64][YROW] = 9216 elems (used only after the main loop)
  __shared__ __align__(16) u16 smem[9728];
  u16* Ksm = smem;          // elem offset (stream*32+key)*KROW + d
  u16* Vsm = smem + 4608;   // elem offset d*VROW + key
  u16* Ysm = smem;          // overlay

  int tid = threadIdx.x;
  int w = tid >> 6, l = tid & 63;
  int q = l & 31, hi = l >> 5;
  int pair = w >> 1, stream = w & 1;
  int bh = blockIdx.y, b = bh >> 4, h = bh & 15;
  int qr0 = blockIdx.x * 64 + pair * 32;

  // lambda
  float lm1 = lq1[h * 64 + l] * lk1[h * 64 + l];
  float lm2 = lq2[h * 64 + l] * lk2[h * 64 + l];
#pragma unroll
  for (int o = 32; o; o >>= 1) {
    lm1 += __shfl_xor(lm1, o);
    lm2 += __shfl_xor(lm2, o);
  }
  float lam = __expf(lm1) - __expf(lm2) + LAMBDA_INIT;

  int soff = stream * 1024;
  const u16* qrow = q1q2 + (size_t)(b * T_SEQ + qr0 + q) * 2048 + h * 64 + soff + hi * 8;
  short8 qf[4];
#pragma unroll
  for (int c = 0; c < 4; ++c) qf[c] = ld8(qrow + c * 16);

  float scale = (mask[b * T_SEQ + qr0 + q] == 0) ? 0.f : SM_SCALE;

  float M = -INFINITY, L = 0.f;
  f32x16 acc[4] = {};

  // staging assignments (per thread: 2 K units + 2 V units of 16B)
  int ku = tid * 2;
  int krow = ku >> 3, kslot = ku & 7;          // same row for both units
  int kstream = krow >> 5, kkey = krow & 31;
  const u16* srcK = k1k2 + (size_t)(b * T_SEQ + kkey) * 2048 + h * 64 + kstream * 1024 + kslot * 8;
  u16* dstK = &Ksm[(kstream * 32 + kkey) * KROW + kslot * 8];
  int vd = tid >> 1, vslot = (tid & 1) * 2;
  const u16* srcV = vvT + ((size_t)(b * 16 + h) * 128 + vd) * 2048 + vslot * 8;
  u16* dstV = &Vsm[vd * VROW + vslot * 8];

  short8 kr0 = ld8(srcK), kr1 = ld8(srcK + 8);
  short8 vr0 = ld8(srcV), vr1 = ld8(srcV + 8);

  for (int kt = 0; kt < T_SEQ; kt += 32) {
    __syncthreads();  // previous tile's reads complete
    st8(dstK, kr0); st8(dstK + 8, kr1);
    st8(dstV, vr0); st8(dstV + 8, vr1);
    __syncthreads();  // tile staged
    if (kt + 32 < T_SEQ) {  // prefetch next tile (overlaps compute)
      const u16* nk = srcK + (size_t)(kt + 32) * 2048;
      kr0 = ld8(nk); kr1 = ld8(nk + 8);
      const u16* nv = srcV + (kt + 32);
      vr0 = ld8(nv); vr1 = ld8(nv + 8);
    }

    // K frags from LDS: lane (q,hi) reads row q of its stream
    const u16* kbase = &Ksm[(stream * 32 + q) * KROW + hi * 8];
    short8 kf[4];
#pragma unroll
    for (int c = 0; c < 4; ++c) kf[c] = ld8(kbase + c * 16);

    f32x16 s = {};
#pragma unroll
    for (int c = 0; c < 4; ++c) s = mfma32(kf[c], qf[c], s);

    float x[16];
#pragma unroll
    for (int r = 0; r < 16; ++r) x[r] = s[r] * scale;

    // tile max: in-lane tree + cross-half
    float t8[8], t4[4];
#pragma unroll
    for (int i = 0; i < 8; ++i) t8[i] = fmaxf(x[i], x[i + 8]);
#pragma unroll
    for (int i = 0; i < 4; ++i) t4[i] = fmaxf(t8[i], t8[i + 4]);
    float tm = fmaxf(fmaxf(t4[0], t4[1]), fmaxf(t4[2], t4[3]));
    tm = fmaxf(tm, __shfl_xor(tm, 32));

    // defer-max (THR=8): rescale only when the tile max outgrows M by >8
    if (!__all(tm - M <= 8.f)) {
      float Mn = fmaxf(M, tm);
      float a = __expf(M - Mn);
      L *= a;
#pragma unroll
      for (int d = 0; d < 4; ++d) acc[d] *= a;
      M = Mn;
    }

    float p[16];
#pragma unroll
    for (int r = 0; r < 16; ++r) p[r] = __expf(x[r] - M);
    float s8[8], s4[4];
#pragma unroll
    for (int i = 0; i < 8; ++i) s8[i] = p[i] + p[i + 8];
#pragma unroll
    for (int i = 0; i < 4; ++i) s4[i] = s8[i] + s8[i + 4];
    float ps = (s4[0] + s4[1]) + (s4[2] + s4[3]);
    ps += __shfl_xor(ps, 32);
    L += ps;

    // P^T B-frags in-register (cvt_pk + cross-half exchange)
    uint32_t a1 = cvtpk(p[0], p[1]), a2 = cvtpk(p[2], p[3]);
    uint32_t b1 = cvtpk(p[4], p[5]), b2 = cvtpk(p[6], p[7]);
    uint32_t c1 = cvtpk(p[8], p[9]), c2 = cvtpk(p[10], p[11]);
    uint32_t d1 = cvtpk(p[12], p[13]), d2 = cvtpk(p[14], p[15]);
    uint32_t sa1 = (uint32_t)__shfl_xor((int)a1, 32), sa2 = (uint32_t)__shfl_xor((int)a2, 32);
    uint32_t sb1 = (uint32_t)__shfl_xor((int)b1, 32), sb2 = (uint32_t)__shfl_xor((int)b2, 32);
    uint32_t sc1 = (uint32_t)__shfl_xor((int)c1, 32), sc2 = (uint32_t)__shfl_xor((int)c2, 32);
    uint32_t sd1 = (uint32_t)__shfl_xor((int)d1, 32), sd2 = (uint32_t)__shfl_xor((int)d2, 32);
    union { uint32_t u[4]; short8 s8v; } pu0, pu1;
    pu0.u[0] = hi ? sb1 : a1;  pu0.u[1] = hi ? sb2 : a2;
    pu0.u[2] = hi ? b1 : sa1;  pu0.u[3] = hi ? b2 : sa2;
    pu1.u[0] = hi ? sd1 : c1;  pu1.u[1] = hi ? sd2 : c2;
    pu1.u[2] = hi ? d1 : sc1;  pu1.u[3] = hi ? d2 : sc2;
    short8 pf0 = pu0.s8v, pf1 = pu1.s8v;

    // swapped PV from LDS V tile
#pragma unroll
    for (int d = 0; d < 4; ++d) {
      const u16* vb0 = &Vsm[(d * 32 + q) * VROW + hi * 8];
      short8 vf0 = ld8(vb0);
      short8 vf1 = ld8(vb0 + 16);
      acc[d] = mfma32(vf0, pf0, acc[d]);
      acc[d] = mfma32(vf1, pf1, acc[d]);
    }
  }

  float inv = 1.f / L;
  __syncthreads();  // Ks/Vs dead -> ylds overlay safe
  if (stream == 1) {
    u16* yrow = &Ysm[(pair * 64 + l) * YROW];
#pragma unroll
    for (int d = 0; d < 4; ++d) {
      union { uint32_t u[8]; short8 v[2]; } pk;
#pragma unroll
      for (int i = 0; i < 8; ++i)
        pk.u[i] = cvtpk(acc[d][2 * i] * inv, acc[d][2 * i + 1] * inv);
      st8(yrow + d * 16, pk.v[0]);
      st8(yrow + d * 16 + 8, pk.v[1]);
    }
  }
  __syncthreads();
  if (stream == 0) {
    const u16* yrow = &Ysm[(pair * 64 + l) * YROW];
    float y[4][16];
#pragma unroll
    for (int d = 0; d < 4; ++d) {
      short8 y2a = ld8(yrow + d * 16);
      short8 y2b = ld8(yrow + d * 16 + 8);
#pragma unroll
      for (int i = 0; i < 8; ++i) {
        y[d][i] = acc[d][i] * inv - lam * b2f((u16)y2a[i]);
        y[d][8 + i] = acc[d][8 + i] * inv - lam * b2f((u16)y2b[i]);
      }
    }
    float sm = 0.f;
#pragma unroll
    for (int d = 0; d < 4; ++d)
#pragma unroll
      for (int r = 0; r < 16; ++r) sm += y[d][r];
    sm += __shfl_xor(sm, 32);
    float u = sm * (1.f / 128.f);
    float var = 0.f;
#pragma unroll
    for (int d = 0; d < 4; ++d)
#pragma unroll
      for (int r = 0; r < 16; ++r) { float dd = y[d][r] - u; var += dd * dd; }
    var += __shfl_xor(var, 32);
    float rstd = rsqrtf(var * (1.f / 128.f) + 1e-12f);

    size_t orow = (size_t)(b * T_SEQ + qr0 + q) * 2048 + h * 128;
#pragma unroll
    for (int d = 0; d < 4; ++d)
#pragma unroll
      for (int rr = 0; rr < 4; ++rr) {
        int base = d * 32 + 8 * rr + 4 * hi;
        union { u16 u[4]; uint2 v; } o;
#pragma unroll
        for (int i = 0; i < 4; ++i) {
          float yv = (lnw[base + i] * ((y[d][rr * 4 + i] - u) * rstd) + lnb[base + i]) *
                     ONE_MINUS_LI;
          o.u[i] = f2bf(yv);
        }
        *reinterpret_cast<uint2*>(&yout[orow + base]) = o.v;
      }
  }
}

// ---------------- host ----------------
extern "C" void kernel_launch(void* const* d_in, const int* in_sizes, int n_in,
                              void* d_out, int out_size, void* d_ws, size_t ws_size,
                              hipStream_t stream) {
  (void)in_sizes; (void)n_in; (void)out_size; (void)ws_size;
  const float* q   = (const float*)d_in[0];
  const float* k   = (const float*)d_in[1];
  const float* v   = (const float*)d_in[2];
  const int* maskp = (const int*)d_in[3];
  const float* Wq1 = (const float*)d_in[4];
  const float* bq1 = (const float*)d_in[5];
  const float* Wq2 = (const float*)d_in[6];
  const float* bq2 = (const float*)d_in[7];
  const float* Wk1 = (const float*)d_in[8];
  const float* bk1 = (const float*)d_in[9];
  const float* Wk2 = (const float*)d_in[10];
  const float* bk2 = (const float*)d_in[11];
  const float* Wv  = (const float*)d_in[12];
  const float* bv  = (const float*)d_in[13];
  const float* Wc  = (const float*)d_in[14];
  const float* bc  = (const float*)d_in[15];
  const float* lnw = (const float*)d_in[16];
  const float* lnb = (const float*)d_in[17];
  const float* lq1 = (const float*)d_in[18];
  const float* lk1 = (const float*)d_in[19];
  const float* lq2 = (const float*)d_in[20];
  const float* lk2 = (const float*)d_in[21];

  char* ws = (char*)d_ws;
  u16* qb     = (u16*)(ws + 0);
  u16* kb     = (u16*)(ws + 8388608);
  u16* vb     = (u16*)(ws + 16777216);
  u16* Wq12T  = (u16*)(ws + 25165824);
  u16* Wk12T  = (u16*)(ws + 29360128);
  u16* WvT    = (u16*)(ws + 33554432);
  u16* WcT    = (u16*)(ws + 37748736);
  float* biasq = (float*)(ws + 41943040);
  float* biask = (float*)(ws + 41951232);
  u16* q1q2   = (u16*)(ws + 41959424);
  u16* k1k2   = (u16*)(ws + 58736640);
  u16* vvT    = (u16*)(ws + 75513856);
  u16* yb     = (u16*)(ws + 0);  // alias qb+kb (16MB; both dead before attention)

  const int NELEM = 2 * T_SEQ * 1024;  // 4,194,304

  cvt_bf16<<<4096, 256, 0, stream>>>(q, qb, NELEM);
  cvt_bf16<<<4096, 256, 0, stream>>>(k, kb, NELEM);
  cvt_bf16<<<4096, 256, 0, stream>>>(v, vb, NELEM);

  tcvt<<<dim3(32, 32), 256, 0, stream>>>(Wq1, Wq12T, 1024, 1024, 0);
  tcvt<<<dim3(32, 32), 256, 0, stream>>>(Wq2, Wq12T, 1024, 1024, 1024);
  tcvt<<<dim3(32, 32), 256, 0, stream>>>(Wk1, Wk12T, 1024, 1024, 0);
  tcvt<<<dim3(32, 32), 256, 0, stream>>>(Wk2, Wk12T, 1024, 1024, 1024);
  tcvt<<<dim3(64, 32), 256, 0, stream>>>(Wv, WvT, 1024, 2048, 0);
  tcvt<<<dim3(32, 64), 256, 0, stream>>>(Wc, WcT, 2048, 1024, 0);

  bias_concat<<<8, 256, 0, stream>>>(bq1, bq2, biasq);
  bias_concat<<<8, 256, 0, stream>>>(bk1, bk2, biask);

  gemm_bt<0><<<dim3(16, 32), 256, 0, stream>>>(qb, Wq12T, biasq, q1q2, 4096, 2048, 1024);
  gemm_bt<0><<<dim3(16, 32), 256, 0, stream>>>(kb, Wk12T, biask, k1k2, 4096, 2048, 1024);
  gemm_bt<1><<<dim3(16, 32), 256, 0, stream>>>(vb, WvT, bv, vvT, 4096, 2048, 1024);

  diffattn<<<dim3(32, 32), 256, 0, stream>>>(q1q2, k1k2, vvT, maskp,
                                             lq1, lk1, lq2, lk2, lnw, lnb, yb);

  gemm_bt<2><<<dim3(8, 32), 256, 0, stream>>>(yb, WcT, bc, d_out, 4096, 1024, 2048);
}